// Round 9
// baseline (542.342 us; speedup 1.0000x reference)
//
#include <hip/hip_runtime.h>
#include <hip/hip_fp16.h>

#define N_NODES 50000
#define N_EDGES 800000
#define IN_DIM  128
#define OUT_DIM 256
#define WT_STRIDE 136  // f16 elems; 272B rows -> 2-way-max bank spread (free)
#define NBLK 1024      // mega kernel grid; co-resident by __launch_bounds__(256,4)
#define NODES_PER_BLK 49  // 1024*49 = 50176 >= 50001

typedef _Float16 f16x8 __attribute__((ext_vector_type(8)));
typedef float f32x4 __attribute__((ext_vector_type(4)));

// ---------------------------------------------------------------------------
// Uniform int64-vs-int32 detection (values < 2^31 -> int64 odd words all 0).
// ---------------------------------------------------------------------------
__device__ __forceinline__ int detect_i64(const int* __restrict__ idx) {
  int orv = 0;
#pragma unroll
  for (int j = 1; j < 32; j += 2) orv |= idx[j];
  return orv == 0;
}

// ---------------------------------------------------------------------------
// Grid barrier (sense-reversal). SAFE ONLY because all NBLK blocks are
// co-resident: grid=1024, __launch_bounds__(256,4) => 4 blocks/CU * 256 CUs.
// counter/gen zeroed by the memset node before each launch.
// ---------------------------------------------------------------------------
__device__ __forceinline__ void grid_barrier(int* counter, int* gen) {
  __syncthreads();
  if (threadIdx.x == 0) {
    __threadfence();  // make prior plain stores visible device-wide
    int g = __hip_atomic_load(gen, __ATOMIC_RELAXED, __HIP_MEMORY_SCOPE_AGENT);
    int prev = __hip_atomic_fetch_add(counter, 1, __ATOMIC_ACQ_REL,
                                      __HIP_MEMORY_SCOPE_AGENT);
    if (prev == NBLK - 1) {
      __hip_atomic_store(counter, 0, __ATOMIC_RELAXED,
                         __HIP_MEMORY_SCOPE_AGENT);
      __hip_atomic_store(gen, g + 1, __ATOMIC_RELEASE,
                         __HIP_MEMORY_SCOPE_AGENT);
    } else {
      while (__hip_atomic_load(gen, __ATOMIC_ACQUIRE,
                               __HIP_MEMORY_SCOPE_AGENT) == g) {
        __builtin_amdgcn_s_sleep(2);
      }
    }
  }
  __syncthreads();
}

// ---------------------------------------------------------------------------
// Mega CSR kernel: replaces hist_cast + scan_block + scan_add + scatter
// (4 graph nodes -> 1). Phases separated by grid barriers:
//   A: feat f32->f16 cast | W transpose->WT16g | dst histogram + slot
//   B: two-level exclusive scan of hist -> row_start
//   C: scatter src into dst-sorted esrc (atomic-free via slot)
// ---------------------------------------------------------------------------
__global__ __launch_bounds__(256, 4) void mega_csr(
    const float* __restrict__ feat, const float* __restrict__ W,
    const int* __restrict__ src, const int* __restrict__ dst,
    __half* __restrict__ feat16, __half* __restrict__ WT16g,
    int* __restrict__ hist, int* __restrict__ slot,
    int* __restrict__ row_start, int* __restrict__ bsum,
    int* __restrict__ esrc, int* __restrict__ bar) {
  const int tid = threadIdx.x;
  const int b = blockIdx.x;
  const int gtid = b * 256 + tid;
  const int fd = detect_i64(dst);

  // ---- Phase A ----
  // feat cast: 800000 8-float chunks.
  for (int t = gtid; t < (N_NODES * IN_DIM) / 8; t += NBLK * 256) {
    size_t i = (size_t)t * 8;
    float4 v0 = *reinterpret_cast<const float4*>(feat + i);
    float4 v1 = *reinterpret_cast<const float4*>(feat + i + 4);
    __half2 h[4];
    h[0] = __floats2half2_rn(v0.x, v0.y);
    h[1] = __floats2half2_rn(v0.z, v0.w);
    h[2] = __floats2half2_rn(v1.x, v1.y);
    h[3] = __floats2half2_rn(v1.z, v1.w);
    *reinterpret_cast<float4*>(feat16 + i) = *reinterpret_cast<float4*>(h);
  }
  // W transpose: WT16g[n*128+k] = W[k*256+n].
  if (gtid < OUT_DIM * IN_DIM) {
    int k = gtid & (IN_DIM - 1);
    int n = gtid >> 7;
    WT16g[gtid] = __float2half(W[k * OUT_DIM + n]);
  }
  // dst histogram + slot.
  for (int e = gtid; e < N_EDGES; e += NBLK * 256) {
    int d = dst[fd ? 2 * (long)e : (long)e];
    slot[e] = atomicAdd(&hist[d], 1);
  }

  grid_barrier(bar, bar + 1);  // B1: hist/slot complete

  // ---- Phase B: scan ----
  __shared__ int s[64];
  __shared__ int sb[256];
  int v = 0;
  if (tid < 64) {
    int node = b * NODES_PER_BLK + tid;
    v = (tid < NODES_PER_BLK && node < N_NODES) ? hist[node] : 0;
    s[tid] = v;
  }
  __syncthreads();
  for (int off = 1; off < 64; off <<= 1) {
    int t2 = (tid < 64 && tid >= off) ? s[tid - off] : 0;
    __syncthreads();
    if (tid < 64) s[tid] += t2;
    __syncthreads();
  }
  if (tid == 0) bsum[b] = s[NODES_PER_BLK - 1];  // block total (inclusive)

  grid_barrier(bar, bar + 1);  // B2: all bsum written

  int part = 0;
  for (int i = tid; i < b; i += 256) part += bsum[i];
  sb[tid] = part;
  __syncthreads();
  for (int off = 128; off > 0; off >>= 1) {
    if (tid < off) sb[tid] += sb[tid + off];
    __syncthreads();
  }
  int offset = sb[0];
  if (tid < NODES_PER_BLK) {
    int node = b * NODES_PER_BLK + tid;
    if (node < N_NODES) row_start[node] = (s[tid] - v) + offset;
  }
  if (gtid == 0) row_start[N_NODES] = N_EDGES;

  grid_barrier(bar, bar + 1);  // B3: row_start complete

  // ---- Phase C: scatter (2 edges per unit, vector loads) ----
  const int fs = detect_i64(src);
  for (int t = gtid; t < N_EDGES / 2; t += NBLK * 256) {
    int s0, s1, d0, d1;
    if (fs) {
      int4 sv = *reinterpret_cast<const int4*>(src + 4 * (long)t);
      int4 dv = *reinterpret_cast<const int4*>(dst + 4 * (long)t);
      s0 = sv.x; s1 = sv.z; d0 = dv.x; d1 = dv.z;
    } else {
      int2 sv = *reinterpret_cast<const int2*>(src + 2 * (long)t);
      int2 dv = *reinterpret_cast<const int2*>(dst + 2 * (long)t);
      s0 = sv.x; s1 = sv.y; d0 = dv.x; d1 = dv.y;
    }
    int2 sl = *reinterpret_cast<const int2*>(slot + 2 * (long)t);
    esrc[row_start[d0] + sl.x] = s0;
    esrc[row_start[d1] + sl.y] = s1;
  }
}

// ---------------------------------------------------------------------------
// Pull aggregation (round-8 proven, unchanged): one wave per node, unroll-4
// with clean scalar tail. x = 0.5*(feat + mean_neigh), stored fp16.
// ---------------------------------------------------------------------------
__global__ __launch_bounds__(256) void aggregate_f16(
    const float* __restrict__ feat, const __half* __restrict__ feat16,
    const int* __restrict__ esrc, const int* __restrict__ row_start,
    __half2* __restrict__ x) {
  int node = blockIdx.x * 4 + ((int)threadIdx.x >> 6);
  int lane = (int)threadIdx.x & 63;
  if (node >= N_NODES) return;
  int rs = row_start[node];
  int re = row_start[node + 1];
  float2 a0 = {0.f, 0.f}, a1 = {0.f, 0.f}, a2 = {0.f, 0.f}, a3 = {0.f, 0.f};
  int e = rs;
  for (; e + 3 < re; e += 4) {
    int s0 = esrc[e + 0];
    int s1 = esrc[e + 1];
    int s2 = esrc[e + 2];
    int s3 = esrc[e + 3];
    float2 v0 = __half22float2(*reinterpret_cast<const __half2*>(
        feat16 + (size_t)s0 * IN_DIM + lane * 2));
    float2 v1 = __half22float2(*reinterpret_cast<const __half2*>(
        feat16 + (size_t)s1 * IN_DIM + lane * 2));
    float2 v2 = __half22float2(*reinterpret_cast<const __half2*>(
        feat16 + (size_t)s2 * IN_DIM + lane * 2));
    float2 v3 = __half22float2(*reinterpret_cast<const __half2*>(
        feat16 + (size_t)s3 * IN_DIM + lane * 2));
    a0.x += v0.x; a0.y += v0.y;
    a1.x += v1.x; a1.y += v1.y;
    a2.x += v2.x; a2.y += v2.y;
    a3.x += v3.x; a3.y += v3.y;
  }
  for (; e < re; ++e) {
    float2 v0 = __half22float2(*reinterpret_cast<const __half2*>(
        feat16 + (size_t)esrc[e] * IN_DIM + lane * 2));
    a0.x += v0.x; a0.y += v0.y;
  }
  float deg = (float)(re - rs);
  float rdeg = (deg > 0.f) ? 1.0f / deg : 0.0f;
  float2 f = *reinterpret_cast<const float2*>(
      feat + (size_t)node * IN_DIM + lane * 2);
  float x0 = (f.x + ((a0.x + a1.x) + (a2.x + a3.x)) * rdeg) * 0.5f;
  float x1 = (f.y + ((a0.y + a1.y) + (a2.y + a3.y)) * rdeg) * 0.5f;
  x[(size_t)node * (IN_DIM / 2) + lane] = __floats2half2_rn(x0, x1);
}

// ---------------------------------------------------------------------------
// MFMA GEMM (round-8 proven, unchanged): 256 thr / 4 waves / 128 rows,
// WT staged from pre-transposed WT16g via pure b128 copy, 68 KiB LDS.
// C/D layout (m89-verified): col=lane&15, row=(lane>>4)*4+reg.
// ---------------------------------------------------------------------------
__global__ __launch_bounds__(256) void mfma_gemm(
    const _Float16* __restrict__ x, const __half* __restrict__ WT16g,
    float* __restrict__ out) {
  __shared__ _Float16 WT[OUT_DIM * WT_STRIDE];

  const int tid = threadIdx.x;
#pragma unroll
  for (int i = 0; i < 16; ++i) {
    int c = i * 256 + tid;
    int n = c >> 4;
    int kc = c & 15;
    *reinterpret_cast<float4*>(&WT[n * WT_STRIDE + kc * 8]) =
        *reinterpret_cast<const float4*>(WT16g + c * 8);
  }
  __syncthreads();

  const int wave = tid >> 6;
  const int lane = tid & 63;
  const int m = lane & 15;
  const int g = lane >> 4;
  const long row_base = (long)blockIdx.x * 128 + wave * 32;

  f16x8 a[2][4];
#pragma unroll
  for (int rt = 0; rt < 2; ++rt) {
    long row = row_base + rt * 16 + m;
#pragma unroll
    for (int kt = 0; kt < 4; ++kt) {
      if (row < N_NODES) {
        a[rt][kt] = *reinterpret_cast<const f16x8*>(
            x + row * IN_DIM + kt * 32 + g * 8);
      } else {
        a[rt][kt] = f16x8{};
      }
    }
  }

#pragma unroll
  for (int nt = 0; nt < 16; ++nt) {
    f16x8 bfr[4];
#pragma unroll
    for (int kt = 0; kt < 4; ++kt) {
      bfr[kt] = *reinterpret_cast<const f16x8*>(
          &WT[(nt * 16 + m) * WT_STRIDE + kt * 32 + g * 8]);
    }
    f32x4 acc0 = {0.f, 0.f, 0.f, 0.f};
    f32x4 acc1 = {0.f, 0.f, 0.f, 0.f};
#pragma unroll
    for (int kt = 0; kt < 4; ++kt) {
      acc0 = __builtin_amdgcn_mfma_f32_16x16x32_f16(a[0][kt], bfr[kt], acc0, 0, 0, 0);
      acc1 = __builtin_amdgcn_mfma_f32_16x16x32_f16(a[1][kt], bfr[kt], acc1, 0, 0, 0);
    }
    const int col = nt * 16 + m;
#pragma unroll
    for (int j = 0; j < 4; ++j) {
      long r0 = row_base + g * 4 + j;
      long r1 = row_base + 16 + g * 4 + j;
      if (r0 < N_NODES)
        __builtin_nontemporal_store(fmaxf(acc0[j], 0.f),
                                    &out[r0 * OUT_DIM + col]);
      if (r1 < N_NODES)
        __builtin_nontemporal_store(fmaxf(acc1[j], 0.f),
                                    &out[r1 * OUT_DIM + col]);
    }
  }
}

extern "C" void kernel_launch(void* const* d_in, const int* in_sizes, int n_in,
                              void* d_out, int out_size, void* d_ws,
                              size_t ws_size, hipStream_t stream) {
  const float* feat = (const float*)d_in[0];
  const float* W = (const float*)d_in[1];
  const int* src = (const int*)d_in[2];
  const int* dst = (const int*)d_in[3];
  float* out = (float*)d_out;

  // Workspace (~29.3 MB; f16 path proven to fit in rounds 5-8).
  // slot aliases x: slot dies (mega phase C) before x is born (aggregate).
  char* p = (char*)d_ws;
  __half* x = (__half*)p;    p += (size_t)N_NODES * IN_DIM * 2;  // 12.8 MB
  int* slot = (int*)x;                                           // 3.2 MB alias
  int* esrc = (int*)p;       p += (size_t)N_EDGES * 4;           // 3.2 MB
  int* hist = (int*)p;       p += (size_t)N_NODES * 4;           // 200 KB
  int* bar = (int*)p;        p += 16;                            // barrier state
  int* row_start = (int*)p;  p += (size_t)(N_NODES + 1) * 4;
  int* bsum = (int*)p;       p += (size_t)NBLK * 4;
  p = (char*)(((uintptr_t)p + 15) & ~(uintptr_t)15);
  __half* WT16g = (__half*)p; p += (size_t)OUT_DIM * IN_DIM * 2;  // 64 KB
  __half* feat16 = (__half*)p;

  // Zero hist + barrier counters (contiguous) in one memset node.
  hipMemsetAsync(hist, 0, (size_t)N_NODES * 4 + 16, stream);

  mega_csr<<<NBLK, 256, 0, stream>>>(feat, W, src, dst, feat16, WT16g, hist,
                                     slot, row_start, bsum, esrc, bar);
  aggregate_f16<<<(N_NODES + 3) / 4, 256, 0, stream>>>(feat, feat16, esrc,
                                                       row_start, (__half2*)x);
  mfma_gemm<<<(N_NODES + 127) / 128, 256, 0, stream>>>(
      (const _Float16*)x, WT16g, out);
}

// Round 11
// 248.835 us; speedup vs baseline: 2.1795x; 2.1795x over previous
//
#include <hip/hip_runtime.h>
#include <hip/hip_fp16.h>

#define N_NODES 50000
#define N_EDGES 800000
#define IN_DIM  128
#define OUT_DIM 256
#define WT_STRIDE 136   // f16 elems; 272B rows -> 2-way-max bank spread (free)
#define NBLK 512        // co-resident: __launch_bounds__(256,2) => >=2 blocks/CU
#define NODES_PER_BLK 98  // 512*98 = 50176 >= 50001

typedef _Float16 f16x8 __attribute__((ext_vector_type(8)));
typedef float f32x4 __attribute__((ext_vector_type(4)));

#define ATOMIC_LD(p) \
  __hip_atomic_load((p), __ATOMIC_RELAXED, __HIP_MEMORY_SCOPE_AGENT)
#define ATOMIC_ST(p, v) \
  __hip_atomic_store((p), (v), __ATOMIC_RELAXED, __HIP_MEMORY_SCOPE_AGENT)

// ---------------------------------------------------------------------------
// Uniform int64-vs-int32 detection (values < 2^31 -> int64 odd words all 0).
// ---------------------------------------------------------------------------
__device__ __forceinline__ int detect_i64(const int* __restrict__ idx) {
  int orv = 0;
#pragma unroll
  for (int j = 1; j < 32; j += 2) orv |= idx[j];
  return orv == 0;
}

// ---------------------------------------------------------------------------
// Flush-free grid barrier. Monotonic counter per phase (no reset/reuse race).
// __syncthreads() drains each wave's vmcnt -> this block's sc1 stores are at
// the coherence point before the arrive-RMW. Relaxed atomics only: RMW and
// polling loads execute MALL-side (sc1), no L2 writeback/invalidate is ever
// issued — this was the round-9 425 us bug.
// ---------------------------------------------------------------------------
__device__ __forceinline__ void grid_barrier(int* cnt) {
  __syncthreads();
  if (threadIdx.x == 0) {
    __hip_atomic_fetch_add(cnt, 1, __ATOMIC_RELAXED, __HIP_MEMORY_SCOPE_AGENT);
    while (ATOMIC_LD(cnt) < NBLK) __builtin_amdgcn_s_sleep(4);
  }
  __syncthreads();
}

// ---------------------------------------------------------------------------
// Mega CSR kernel (4 graph nodes -> 1). Cross-block data inside this kernel
// (hist, slot, bsum, row_start) moves via relaxed agent-scope atomics; data
// consumed by LATER DISPATCHES (feat16, WT16g, esrc) uses plain cached
// stores (kernel-boundary coherence, proven rounds 2-8).
//   A: feat f32->f16 cast | W transpose->WT16g | dst histogram + slot
//   B: two-level exclusive scan of hist -> row_start
//   C: scatter src into dst-sorted esrc (atomic-free via slot)
// ---------------------------------------------------------------------------
__global__ __launch_bounds__(256, 2) void mega_csr(
    const float* __restrict__ feat, const float* __restrict__ W,
    const int* __restrict__ src, const int* __restrict__ dst,
    __half* __restrict__ feat16, __half* __restrict__ WT16g,
    int* __restrict__ hist, int* __restrict__ slot,
    int* __restrict__ row_start, int* __restrict__ bsum,
    int* __restrict__ esrc, int* __restrict__ bar) {
  const int tid = threadIdx.x;
  const int b = blockIdx.x;
  const int gtid = b * 256 + tid;
  const int fd = detect_i64(dst);

  // ---- Phase A ----
  for (int t = gtid; t < (N_NODES * IN_DIM) / 8; t += NBLK * 256) {
    size_t i = (size_t)t * 8;
    float4 v0 = *reinterpret_cast<const float4*>(feat + i);
    float4 v1 = *reinterpret_cast<const float4*>(feat + i + 4);
    __half2 h[4];
    h[0] = __floats2half2_rn(v0.x, v0.y);
    h[1] = __floats2half2_rn(v0.z, v0.w);
    h[2] = __floats2half2_rn(v1.x, v1.y);
    h[3] = __floats2half2_rn(v1.z, v1.w);
    *reinterpret_cast<float4*>(feat16 + i) = *reinterpret_cast<float4*>(h);
  }
  if (gtid < OUT_DIM * IN_DIM) {  // WT16g[n*128+k] = W[k*256+n]
    int k = gtid & (IN_DIM - 1);
    int n = gtid >> 7;
    WT16g[gtid] = __float2half(W[k * OUT_DIM + n]);
  }
  for (int e = gtid; e < N_EDGES; e += NBLK * 256) {
    int d = dst[fd ? 2 * (long)e : (long)e];
    int sl = atomicAdd(&hist[d], 1);  // device-scope RMW: coherence point
    ATOMIC_ST(&slot[e], sl);          // sc1 store: no dirty L2 line
  }

  grid_barrier(&bar[0]);  // hist/slot globally visible

  // ---- Phase B: two-level exclusive scan (hist -> row_start) ----
  __shared__ int s[128];
  __shared__ int sb[256];
  int v = 0;
  if (tid < 128) {
    int node = b * NODES_PER_BLK + tid;
    v = (tid < NODES_PER_BLK && node < N_NODES) ? ATOMIC_LD(&hist[node]) : 0;
    s[tid] = v;
  }
  __syncthreads();
  for (int off = 1; off < 128; off <<= 1) {
    int t2 = (tid < 128 && tid >= off) ? s[tid - off] : 0;
    __syncthreads();
    if (tid < 128) s[tid] += t2;
    __syncthreads();
  }
  if (tid == 0) ATOMIC_ST(&bsum[b], s[NODES_PER_BLK - 1]);

  grid_barrier(&bar[32]);  // all bsum visible

  int part = 0;
  for (int i = tid; i < b; i += 256) part += ATOMIC_LD(&bsum[i]);
  sb[tid] = part;
  __syncthreads();
  for (int off = 128; off > 0; off >>= 1) {
    if (tid < off) sb[tid] += sb[tid + off];
    __syncthreads();
  }
  int offset = sb[0];
  if (tid < NODES_PER_BLK) {
    int node = b * NODES_PER_BLK + tid;
    if (node < N_NODES) ATOMIC_ST(&row_start[node], (s[tid] - v) + offset);
  }
  if (gtid == 0) ATOMIC_ST(&row_start[N_NODES], N_EDGES);

  grid_barrier(&bar[64]);  // row_start visible

  // ---- Phase C: scatter (2 edges per unit; esrc plain stores, consumed by
  // the next dispatch). slot/row_start read via sc1 (never L2-cached). ----
  const int fs = detect_i64(src);
  for (int t = gtid; t < N_EDGES / 2; t += NBLK * 256) {
    int s0, s1, d0, d1;
    if (fs) {
      int4 sv = *reinterpret_cast<const int4*>(src + 4 * (long)t);
      int4 dv = *reinterpret_cast<const int4*>(dst + 4 * (long)t);
      s0 = sv.x; s1 = sv.z; d0 = dv.x; d1 = dv.z;
    } else {
      int2 sv = *reinterpret_cast<const int2*>(src + 2 * (long)t);
      int2 dv = *reinterpret_cast<const int2*>(dst + 2 * (long)t);
      s0 = sv.x; s1 = sv.y; d0 = dv.x; d1 = dv.y;
    }
    unsigned long long slv =
        __hip_atomic_load((const unsigned long long*)(slot + 2 * (long)t),
                          __ATOMIC_RELAXED, __HIP_MEMORY_SCOPE_AGENT);
    int sl0 = (int)(slv & 0xffffffffu);
    int sl1 = (int)(slv >> 32);
    int rs0 = ATOMIC_LD(&row_start[d0]);
    int rs1 = ATOMIC_LD(&row_start[d1]);
    esrc[rs0 + sl0] = s0;
    esrc[rs1 + sl1] = s1;
  }
}

// ---------------------------------------------------------------------------
// Pull aggregation (round-8 proven, unchanged): one wave per node, unroll-4
// with clean scalar tail. x = 0.5*(feat + mean_neigh), stored fp16.
// ---------------------------------------------------------------------------
__global__ __launch_bounds__(256) void aggregate_f16(
    const float* __restrict__ feat, const __half* __restrict__ feat16,
    const int* __restrict__ esrc, const int* __restrict__ row_start,
    __half2* __restrict__ x) {
  int node = blockIdx.x * 4 + ((int)threadIdx.x >> 6);
  int lane = (int)threadIdx.x & 63;
  if (node >= N_NODES) return;
  int rs = row_start[node];
  int re = row_start[node + 1];
  float2 a0 = {0.f, 0.f}, a1 = {0.f, 0.f}, a2 = {0.f, 0.f}, a3 = {0.f, 0.f};
  int e = rs;
  for (; e + 3 < re; e += 4) {
    int s0 = esrc[e + 0];
    int s1 = esrc[e + 1];
    int s2 = esrc[e + 2];
    int s3 = esrc[e + 3];
    float2 v0 = __half22float2(*reinterpret_cast<const __half2*>(
        feat16 + (size_t)s0 * IN_DIM + lane * 2));
    float2 v1 = __half22float2(*reinterpret_cast<const __half2*>(
        feat16 + (size_t)s1 * IN_DIM + lane * 2));
    float2 v2 = __half22float2(*reinterpret_cast<const __half2*>(
        feat16 + (size_t)s2 * IN_DIM + lane * 2));
    float2 v3 = __half22float2(*reinterpret_cast<const __half2*>(
        feat16 + (size_t)s3 * IN_DIM + lane * 2));
    a0.x += v0.x; a0.y += v0.y;
    a1.x += v1.x; a1.y += v1.y;
    a2.x += v2.x; a2.y += v2.y;
    a3.x += v3.x; a3.y += v3.y;
  }
  for (; e < re; ++e) {
    float2 v0 = __half22float2(*reinterpret_cast<const __half2*>(
        feat16 + (size_t)esrc[e] * IN_DIM + lane * 2));
    a0.x += v0.x; a0.y += v0.y;
  }
  float deg = (float)(re - rs);
  float rdeg = (deg > 0.f) ? 1.0f / deg : 0.0f;
  float2 f = *reinterpret_cast<const float2*>(
      feat + (size_t)node * IN_DIM + lane * 2);
  float x0 = (f.x + ((a0.x + a1.x) + (a2.x + a3.x)) * rdeg) * 0.5f;
  float x1 = (f.y + ((a0.y + a1.y) + (a2.y + a3.y)) * rdeg) * 0.5f;
  x[(size_t)node * (IN_DIM / 2) + lane] = __floats2half2_rn(x0, x1);
}

// ---------------------------------------------------------------------------
// MFMA GEMM (round-8 proven, unchanged): 256 thr / 4 waves / 128 rows,
// WT staged from pre-transposed WT16g via pure b128 copy, 68 KiB LDS.
// C/D layout (m89-verified): col=lane&15, row=(lane>>4)*4+reg.
// ---------------------------------------------------------------------------
__global__ __launch_bounds__(256) void mfma_gemm(
    const _Float16* __restrict__ x, const __half* __restrict__ WT16g,
    float* __restrict__ out) {
  __shared__ _Float16 WT[OUT_DIM * WT_STRIDE];

  const int tid = threadIdx.x;
#pragma unroll
  for (int i = 0; i < 16; ++i) {
    int c = i * 256 + tid;
    int n = c >> 4;
    int kc = c & 15;
    *reinterpret_cast<float4*>(&WT[n * WT_STRIDE + kc * 8]) =
        *reinterpret_cast<const float4*>(WT16g + c * 8);
  }
  __syncthreads();

  const int wave = tid >> 6;
  const int lane = tid & 63;
  const int m = lane & 15;
  const int g = lane >> 4;
  const long row_base = (long)blockIdx.x * 128 + wave * 32;

  f16x8 a[2][4];
#pragma unroll
  for (int rt = 0; rt < 2; ++rt) {
    long row = row_base + rt * 16 + m;
#pragma unroll
    for (int kt = 0; kt < 4; ++kt) {
      if (row < N_NODES) {
        a[rt][kt] = *reinterpret_cast<const f16x8*>(
            x + row * IN_DIM + kt * 32 + g * 8);
      } else {
        a[rt][kt] = f16x8{};
      }
    }
  }

#pragma unroll
  for (int nt = 0; nt < 16; ++nt) {
    f16x8 bfr[4];
#pragma unroll
    for (int kt = 0; kt < 4; ++kt) {
      bfr[kt] = *reinterpret_cast<const f16x8*>(
          &WT[(nt * 16 + m) * WT_STRIDE + kt * 32 + g * 8]);
    }
    f32x4 acc0 = {0.f, 0.f, 0.f, 0.f};
    f32x4 acc1 = {0.f, 0.f, 0.f, 0.f};
#pragma unroll
    for (int kt = 0; kt < 4; ++kt) {
      acc0 = __builtin_amdgcn_mfma_f32_16x16x32_f16(a[0][kt], bfr[kt], acc0, 0, 0, 0);
      acc1 = __builtin_amdgcn_mfma_f32_16x16x32_f16(a[1][kt], bfr[kt], acc1, 0, 0, 0);
    }
    const int col = nt * 16 + m;
#pragma unroll
    for (int j = 0; j < 4; ++j) {
      long r0 = row_base + g * 4 + j;
      long r1 = row_base + 16 + g * 4 + j;
      if (r0 < N_NODES)
        __builtin_nontemporal_store(fmaxf(acc0[j], 0.f),
                                    &out[r0 * OUT_DIM + col]);
      if (r1 < N_NODES)
        __builtin_nontemporal_store(fmaxf(acc1[j], 0.f),
                                    &out[r1 * OUT_DIM + col]);
    }
  }
}

extern "C" void kernel_launch(void* const* d_in, const int* in_sizes, int n_in,
                              void* d_out, int out_size, void* d_ws,
                              size_t ws_size, hipStream_t stream) {
  const float* feat = (const float*)d_in[0];
  const float* W = (const float*)d_in[1];
  const int* src = (const int*)d_in[2];
  const int* dst = (const int*)d_in[3];
  float* out = (float*)d_out;

  // Workspace (~29.3 MB; proven to fit rounds 5-9).
  // slot aliases x: slot dies (mega phase C) before x is born (aggregate).
  char* p = (char*)d_ws;
  __half* x = (__half*)p;    p += (size_t)N_NODES * IN_DIM * 2;  // 12.8 MB
  int* slot = (int*)x;                                           // 3.2 MB alias
  int* esrc = (int*)p;       p += (size_t)N_EDGES * 4;           // 3.2 MB
  int* hist = (int*)p;       p += (size_t)N_NODES * 4;           // 200 KB
  int* bar = (int*)p;        p += 96 * 4;  // 3 slots, 128B apart
  int* row_start = (int*)p;  p += (size_t)(N_NODES + 1) * 4;
  int* bsum = (int*)p;       p += (size_t)NBLK * 4;
  p = (char*)(((uintptr_t)p + 15) & ~(uintptr_t)15);
  __half* WT16g = (__half*)p; p += (size_t)OUT_DIM * IN_DIM * 2;  // 64 KB
  __half* feat16 = (__half*)p;

  // One memset node: hist + barrier slots (contiguous).
  hipMemsetAsync(hist, 0, (size_t)N_NODES * 4 + 96 * 4, stream);

  mega_csr<<<NBLK, 256, 0, stream>>>(feat, W, src, dst, feat16, WT16g, hist,
                                     slot, row_start, bsum, esrc, bar);
  aggregate_f16<<<(N_NODES + 3) / 4, 256, 0, stream>>>(feat, feat16, esrc,
                                                       row_start, (__half2*)x);
  mfma_gemm<<<(N_NODES + 127) / 128, 256, 0, stream>>>(
      (const _Float16*)x, WT16g, out);
}